// Round 2
// baseline (1823.498 us; speedup 1.0000x reference)
//
#include <hip/hip_runtime.h>
#include <hip/hip_bf16.h>
#include <math.h>

typedef __hip_bfloat16 bf16;

#define HH 512
#define WWI 512
#define HWP (HH*WWI)

__device__ __forceinline__ float b2f(bf16 v) { return __bfloat162float(v); }

// load input element i from p, honoring detected input dtype (isbf: 1=bf16, 0=fp32)
__device__ __forceinline__ float ldin(const void* p, long i, int isbf) {
  return isbf ? __bfloat162float(((const bf16*)p)[i]) : ((const float*)p)[i];
}

// ---------------- dtype detector ----------------
// Scan w1 (38016 elems of N(0,~0.04)) reinterpreted as bf16 halves.
// True bf16 inputs: all values tiny. fp32 inputs: low-half mantissa words give
// random exponents -> some |v| huge/NaN. flag=1 means inputs are bf16.
__global__ void k_detect(const void* w1, int* flag) {
  __shared__ int bad;
  if (threadIdx.x == 0) bad = 0;
  __syncthreads();
  const bf16* p = (const bf16*)w1;
  int local = 0;
  for (int i = threadIdx.x; i < 38016; i += blockDim.x) {
    float v = __bfloat162float(p[i]);
    if (!(fabsf(v) < 512.f)) local = 1;   // catches NaN/Inf too
  }
  if (local) atomicOr(&bad, 1);
  __syncthreads();
  if (threadIdx.x == 0) flag[0] = bad ? 0 : 1;
}

// ---------------- weight/bias -> fp32 (dict order w0,b0,...,w8,b8,wf,bf) ----------------
__global__ void k_convert(
    const void* p0, const void* p1, const void* p2, const void* p3, const void* p4,
    const void* p5, const void* p6, const void* p7, const void* p8, const void* p9,
    const void* p10, const void* p11, const void* p12, const void* p13, const void* p14,
    const void* p15, const void* p16, const void* p17, const void* p18, const void* p19,
    float* __restrict__ out, const int* __restrict__ flag)
{
  const int offs[21] = {0,192,256,38272,38336,75200,75264,93696,93728,102944,102976,
                        112192,112224,116832,116848,119152,119168,121472,121488,122352,122358};
  const void* ptrs[20] = {p0,p1,p2,p3,p4,p5,p6,p7,p8,p9,p10,p11,p12,p13,p14,p15,p16,p17,p18,p19};
  int i = blockIdx.x*blockDim.x + threadIdx.x;
  if (i >= 122358) return;
  int isbf = flag[0];
  int s = 0;
  while (s < 19 && i >= offs[s+1]) s++;
  out[i] = ldin(ptrs[s], i - offs[s], isbf);
}

// ---------------- layer 0: 1x1 conv on upsampled 2x2 + leakyrelu + coordconv ----------------
__global__ void k_layer0(const void* __restrict__ xin, const float* __restrict__ w,
                         const float* __restrict__ bias, float* __restrict__ out,
                         const int* __restrict__ flag)
{
  int isbf = flag[0];
  for (int idx = threadIdx.x; idx < 3*66*4; idx += blockDim.x) {
    int pos = idx & 3;
    int c = (idx >> 2) % 66;
    int b = idx / (66*4);
    float v;
    if (c < 64) {
      float a = bias[c];
      #pragma unroll
      for (int ci = 0; ci < 3; ci++) a += w[c*3+ci] * ldin(xin, b*3+ci, isbf);
      v = (a >= 0.f) ? a : 0.01f*a;
    } else {
      int xx = pos & 1, yy = pos >> 1;
      v = (c == 64) ? 2.f*(float)xx : 2.f*(float)yy;
    }
    out[idx] = v;
  }
}

// reflect(pad=1) on upsampled-by-2 grid of size n, then map to source row
__device__ __forceinline__ int refl_up(int t, int n) {
  t = (t < 0) ? -t : t;
  t = (t >= n) ? (2*(n-1) - t) : t;
  return t >> 1;
}

// ---------------- upsample x2 + reflect-pad + 3x3 VALID conv + leakyrelu ----------------
template<int CO>
__global__ void k_upconv(const float* __restrict__ in, float* __restrict__ out,
                         const float* __restrict__ w, const float* __restrict__ bias,
                         int B, int Cin, int Hin)
{
  int Hout = Hin * 2;
  int total = B * Hout * Hout;
  int idx = blockIdx.x*blockDim.x + threadIdx.x;
  if (idx >= total) return;
  int x = idx % Hout;
  int y = (idx / Hout) % Hout;
  int b = idx / (Hout * Hout);

  int ry[3], rx[3];
  #pragma unroll
  for (int d = 0; d < 3; d++) {
    ry[d] = refl_up(y - 1 + d, Hout);
    rx[d] = refl_up(x - 1 + d, Hout);
  }

  float acc[CO];
  #pragma unroll
  for (int co = 0; co < CO; co++) acc[co] = bias[co];

  for (int ci = 0; ci < Cin; ci++) {
    const float* ib = in + ((size_t)(b*Cin) + ci) * (Hin*Hin);
    float p[9];
    #pragma unroll
    for (int dy = 0; dy < 3; dy++)
      #pragma unroll
      for (int dx = 0; dx < 3; dx++)
        p[dy*3+dx] = ib[ry[dy]*Hin + rx[dx]];
    const float* wc = w + ci*9;
    #pragma unroll
    for (int co = 0; co < CO; co++) {
      const float* wcc = wc + co*Cin*9;
      #pragma unroll
      for (int k = 0; k < 9; k++) acc[co] += wcc[k] * p[k];
    }
  }

  int pix = y*Hout + x;
  #pragma unroll
  for (int co = 0; co < CO; co++) {
    float v = acc[co];
    v = (v >= 0.f) ? v : 0.01f*v;
    out[((size_t)(b*CO) + co)*(Hout*Hout) + pix] = v;
  }
}

// ---------------- final: reflect-pad + 3x3 conv (16 -> 6) + tanh ----------------
__global__ void k_final(const float* __restrict__ in, float* __restrict__ out,
                        const float* __restrict__ w, const float* __restrict__ bias)
{
  int idx = blockIdx.x*blockDim.x + threadIdx.x;
  int total = 3 * HWP;
  if (idx >= total) return;
  int x = idx & (WWI-1);
  int y = (idx >> 9) & (HH-1);
  int b = idx / HWP;

  int ry[3], rx[3];
  #pragma unroll
  for (int d = 0; d < 3; d++) {
    int t = y - 1 + d;
    t = (t < 0) ? -t : t;
    ry[d] = (t >= HH) ? (2*(HH-1) - t) : t;
    t = x - 1 + d;
    t = (t < 0) ? -t : t;
    rx[d] = (t >= WWI) ? (2*(WWI-1) - t) : t;
  }

  float acc[6];
  #pragma unroll
  for (int co = 0; co < 6; co++) acc[co] = bias[co];

  for (int ci = 0; ci < 16; ci++) {
    const float* ib = in + ((size_t)(b*16) + ci) * HWP;
    float p[9];
    #pragma unroll
    for (int dy = 0; dy < 3; dy++)
      #pragma unroll
      for (int dx = 0; dx < 3; dx++)
        p[dy*3+dx] = ib[ry[dy]*WWI + rx[dx]];
    const float* wc = w + ci*9;
    #pragma unroll
    for (int co = 0; co < 6; co++) {
      const float* wcc = wc + co*16*9;
      #pragma unroll
      for (int k = 0; k < 9; k++) acc[co] += wcc[k] * p[k];
    }
  }

  int pix = y*WWI + x;
  #pragma unroll
  for (int co = 0; co < 6; co++)
    out[((size_t)(b*6) + co)*HWP + pix] = tanhf(acc[co]);
}

// ---------------- blending: fused grid-sample + weighting ----------------
__global__ void k_blend(const void* __restrict__ xin, const void* __restrict__ neighbors,
                        const int* __restrict__ aidx, const void* __restrict__ albedos,
                        const float* __restrict__ flows, void* __restrict__ out,
                        const int* __restrict__ flag)
{
  int idx = blockIdx.x*blockDim.x + threadIdx.x;
  if (idx >= HWP) return;
  int isbf = flag[0];
  int xo = idx & (WWI-1);
  int yo = idx >> 9;

  float xv[9];
  #pragma unroll
  for (int i = 0; i < 9; i++) xv[i] = ldin(xin, i, isbf);

  float f0[6];
  #pragma unroll
  for (int c = 0; c < 6; c++) f0[c] = flows[(size_t)c*HWP + idx];

  long albbase = (long)aidx[0]*3*HWP;
  float albp[3];
  #pragma unroll
  for (int ch = 0; ch < 3; ch++) albp[ch] = ldin(albedos, albbase + (long)ch*HWP + idx, isbf);

  float num0 = 0.f, num1 = 0.f, num2 = 0.f;
  float wsum = 0.f;

  #pragma unroll
  for (int n = 0; n < 2; n++) {
    float dl = xv[0] - xv[(n+1)*3 + 0];
    float dv = xv[1] - xv[(n+1)*3 + 1];
    float dt = xv[2] - xv[(n+1)*3 + 2];
    bool fl = fabsf(dl) > 0.f;

    float ofx = dl*f0[0] + dv*f0[2] + dt*f0[4];
    float ofy = dl*f0[1] + dv*f0[3] + dt*f0[5];

    float gx = ((-1.f + (2.f/511.f)*(float)xo) + ofx + 1.f)*256.f - 0.5f;
    float gy = ((-1.f + (2.f/511.f)*(float)yo) + ofy + 1.f)*256.f - 0.5f;
    gx = fminf(fmaxf(gx, 0.f), 511.f);
    gy = fminf(fmaxf(gy, 0.f), 511.f);

    float x0f = floorf(gx), y0f = floorf(gy);
    float wx = gx - x0f, wy = gy - y0f;
    int x0i = (int)x0f, y0i = (int)y0f;
    int x1i = min(x0i + 1, WWI-1), y1i = min(y0i + 1, HH-1);

    float cw[4] = {(1.f-wx)*(1.f-wy), wx*(1.f-wy), (1.f-wx)*wy, wx*wy};
    int   cp[4] = {y0i*WWI + x0i, y0i*WWI + x1i, y1i*WWI + x0i, y1i*WWI + x1i};

    long nbase = (long)n*3*HWP;
    const float* Fn = flows + (size_t)(n+1)*6*HWP;

    float s0=0.f,s1=0.f,s2=0.f;
    float l0=0.f,l1=0.f,v0=0.f,v1=0.f,t0=0.f,t1=0.f;
    #pragma unroll
    for (int c = 0; c < 4; c++) {
      int p = cp[c];
      float ww = cw[c];
      float n0 = ldin(neighbors, nbase + p, isbf);
      float n1 = ldin(neighbors, nbase + HWP + p, isbf);
      float n2 = ldin(neighbors, nbase + 2*HWP + p, isbf);
      if (fl) {
        n0 /= ldin(albedos, albbase + p, isbf);
        n1 /= ldin(albedos, albbase + HWP + p, isbf);
        n2 /= ldin(albedos, albbase + 2*HWP + p, isbf);
      }
      s0 += ww*n0; s1 += ww*n1; s2 += ww*n2;
      l0 += ww*Fn[p];             l1 += ww*Fn[HWP + p];
      v0 += ww*Fn[2*HWP + p];     v1 += ww*Fn[3*HWP + p];
      t0 += ww*Fn[4*HWP + p];     t1 += ww*Fn[5*HWP + p];
    }

    float wi0 = fl ? s0*albp[0] : s0;
    float wi1 = fl ? s1*albp[1] : s1;
    float wi2 = fl ? s2*albp[2] : s2;

    float obx = dl*l0 + dv*v0 + dt*t0;
    float oby = dl*l1 + dv*v1 + dt*t1;
    float dist = fabsf(ofx - obx) + fabsf(ofy - oby);
    float wgt = expf(-51.2f * dist);

    wsum += wgt;
    num0 += wgt*wi0; num1 += wgt*wi1; num2 += wgt*wi2;
  }

  float inv = 1.f / (wsum + 1e-5f);
  float r0 = num0*inv, r1 = num1*inv, r2 = num2*inv;
  if (isbf) {
    bf16* o = (bf16*)out;
    o[idx]         = __float2bfloat16(r0);
    o[HWP + idx]   = __float2bfloat16(r1);
    o[2*HWP + idx] = __float2bfloat16(r2);
  } else {
    float* o = (float*)out;
    o[idx]         = r0;
    o[HWP + idx]   = r1;
    o[2*HWP + idx] = r2;
  }
}

// ---------------- launch ----------------
extern "C" void kernel_launch(void* const* d_in, const int* in_sizes, int n_in,
                              void* d_out, int out_size, void* d_ws, size_t ws_size,
                              hipStream_t stream) {
  const void* x         = d_in[0];
  const void* neighbors = d_in[1];
  const int*  aidx      = (const int*)d_in[2];
  const void* wts[10];
  const void* bis[10];
  for (int i = 0; i < 9; i++) { wts[i] = d_in[3+2*i]; bis[i] = d_in[4+2*i]; }
  wts[9] = d_in[21];   // wf
  bis[9] = d_in[22];   // bf
  const void* albedos = d_in[23];

  // ws layout (floats): [0,8) flag ; [8,122366) wf32 ; [122368,123160) bufS ;
  // [123160, +4718592) bufA ; then bufB 12582912
  float* wk   = (float*)d_ws;
  int*   flagp = (int*)d_ws;
  float* wf32 = wk + 8;
  float* bufS = wk + 122368;
  float* bufA = wk + 123160;
  float* bufB = bufA + 4718592;
  size_t need = (size_t)(123160 + 4718592 + 12582912) * 4;
  if (ws_size < need) return;

  const int o_w0=0, o_b0=192, o_w1=256, o_w2=38336, o_b1=38272, o_b2=75200,
            o_w3=75264, o_b3=93696, o_w4=93728, o_b4=102944, o_w5=102976, o_b5=112192,
            o_w6=112224, o_b6=116832, o_w7=116848, o_b7=119152, o_w8=119168, o_b8=121472,
            o_wf=121488, o_bf=122352;

  k_detect<<<1, 256, 0, stream>>>(wts[1], flagp);

  k_convert<<<(122358+255)/256, 256, 0, stream>>>(
      wts[0],bis[0],wts[1],bis[1],wts[2],bis[2],wts[3],bis[3],wts[4],bis[4],
      wts[5],bis[5],wts[6],bis[6],wts[7],bis[7],wts[8],bis[8],wts[9],bis[9],
      wf32, flagp);

  k_layer0<<<1, 256, 0, stream>>>(x, wf32+o_w0, wf32+o_b0, bufS, flagp);

  auto blocks = [](int total){ return (total + 255) / 256; };

  k_upconv<64><<<blocks(3*4*4),     256, 0, stream>>>(bufS, bufA, wf32+o_w1, wf32+o_b1, 3, 66, 2);
  k_upconv<64><<<blocks(3*8*8),     256, 0, stream>>>(bufA, bufB, wf32+o_w2, wf32+o_b2, 3, 64, 4);
  k_upconv<32><<<blocks(3*16*16),   256, 0, stream>>>(bufB, bufA, wf32+o_w3, wf32+o_b3, 3, 64, 8);
  k_upconv<32><<<blocks(3*32*32),   256, 0, stream>>>(bufA, bufB, wf32+o_w4, wf32+o_b4, 3, 32, 16);
  k_upconv<32><<<blocks(3*64*64),   256, 0, stream>>>(bufB, bufA, wf32+o_w5, wf32+o_b5, 3, 32, 32);
  k_upconv<16><<<blocks(3*128*128), 256, 0, stream>>>(bufA, bufB, wf32+o_w6, wf32+o_b6, 3, 32, 64);
  k_upconv<16><<<blocks(3*256*256), 256, 0, stream>>>(bufB, bufA, wf32+o_w7, wf32+o_b7, 3, 16, 128);
  k_upconv<16><<<blocks(3*512*512), 256, 0, stream>>>(bufA, bufB, wf32+o_w8, wf32+o_b8, 3, 16, 256);
  k_final<<<blocks(3*HWP), 256, 0, stream>>>(bufB, bufA, wf32+o_wf, wf32+o_bf);

  k_blend<<<blocks(HWP), 256, 0, stream>>>(x, neighbors, aidx, albedos, bufA, d_out, flagp);
}

// Round 3
// 638.043 us; speedup vs baseline: 2.8580x; 2.8580x over previous
//
#include <hip/hip_runtime.h>
#include <hip/hip_bf16.h>
#include <math.h>

typedef __hip_bfloat16 bf16;

#define HH 512
#define WWI 512
#define HWP (HH*WWI)

__device__ __forceinline__ float b2f(bf16 v) { return __bfloat162float(v); }

// load input element i from p, honoring detected input dtype (isbf: 1=bf16, 0=fp32)
__device__ __forceinline__ float ldin(const void* p, long i, int isbf) {
  return isbf ? __bfloat162float(((const bf16*)p)[i]) : ((const float*)p)[i];
}

// ---------------- dtype detector ----------------
__global__ void k_detect(const void* w1, int* flag) {
  __shared__ int bad;
  if (threadIdx.x == 0) bad = 0;
  __syncthreads();
  const bf16* p = (const bf16*)w1;
  int local = 0;
  for (int i = threadIdx.x; i < 38016; i += blockDim.x) {
    float v = __bfloat162float(p[i]);
    if (!(fabsf(v) < 512.f)) local = 1;   // catches NaN/Inf too
  }
  if (local) atomicOr(&bad, 1);
  __syncthreads();
  if (threadIdx.x == 0) flag[0] = bad ? 0 : 1;
}

// ---------------- weight/bias -> fp32 (dict order w0,b0,...,w8,b8,wf,bf) ----------------
__global__ void k_convert(
    const void* p0, const void* p1, const void* p2, const void* p3, const void* p4,
    const void* p5, const void* p6, const void* p7, const void* p8, const void* p9,
    const void* p10, const void* p11, const void* p12, const void* p13, const void* p14,
    const void* p15, const void* p16, const void* p17, const void* p18, const void* p19,
    float* __restrict__ out, const int* __restrict__ flag)
{
  const int offs[21] = {0,192,256,38272,38336,75200,75264,93696,93728,102944,102976,
                        112192,112224,116832,116848,119152,119168,121472,121488,122352,122358};
  const void* ptrs[20] = {p0,p1,p2,p3,p4,p5,p6,p7,p8,p9,p10,p11,p12,p13,p14,p15,p16,p17,p18,p19};
  int i = blockIdx.x*blockDim.x + threadIdx.x;
  if (i >= 122358) return;
  int isbf = flag[0];
  int s = 0;
  while (s < 19 && i >= offs[s+1]) s++;
  out[i] = ldin(ptrs[s], i - offs[s], isbf);
}

// ---------------- layer 0 ----------------
__global__ void k_layer0(const void* __restrict__ xin, const float* __restrict__ w,
                         const float* __restrict__ bias, float* __restrict__ out,
                         const int* __restrict__ flag)
{
  int isbf = flag[0];
  for (int idx = threadIdx.x; idx < 3*66*4; idx += blockDim.x) {
    int pos = idx & 3;
    int c = (idx >> 2) % 66;
    int b = idx / (66*4);
    float v;
    if (c < 64) {
      float a = bias[c];
      #pragma unroll
      for (int ci = 0; ci < 3; ci++) a += w[c*3+ci] * ldin(xin, b*3+ci, isbf);
      v = (a >= 0.f) ? a : 0.01f*a;
    } else {
      int xx = pos & 1, yy = pos >> 1;
      v = (c == 64) ? 2.f*(float)xx : 2.f*(float)yy;
    }
    out[idx] = v;
  }
}

__device__ __forceinline__ int refl_up(int t, int n) {
  t = (t < 0) ? -t : t;
  t = (t >= n) ? (2*(n-1) - t) : t;
  return t >> 1;
}

// ---------------- grouped upconv: thread = (b, channel-group of G, pixel) ----------------
// acc[G] only -> no spills; parallelism x (CO/G)
template<int G>
__global__ void k_upconv_g(const float* __restrict__ in, float* __restrict__ out,
                           const float* __restrict__ w, const float* __restrict__ bias,
                           int B, int Cin, int Hin, int CO)
{
  int Hout = Hin * 2;
  int ngroups = CO / G;
  int total = B * ngroups * Hout * Hout;
  int idx = blockIdx.x*blockDim.x + threadIdx.x;
  if (idx >= total) return;
  int x = idx % Hout;
  int y = (idx / Hout) % Hout;
  int rest = idx / (Hout * Hout);
  int gq = rest % ngroups;
  int b  = rest / ngroups;
  int co0 = gq * G;

  int ry[3], rx[3];
  #pragma unroll
  for (int d = 0; d < 3; d++) {
    ry[d] = refl_up(y - 1 + d, Hout);
    rx[d] = refl_up(x - 1 + d, Hout);
  }

  float acc[G];
  #pragma unroll
  for (int j = 0; j < G; j++) acc[j] = bias[co0 + j];

  for (int ci = 0; ci < Cin; ci++) {
    const float* ib = in + ((size_t)(b*Cin) + ci) * (Hin*Hin);
    float p[9];
    #pragma unroll
    for (int dy = 0; dy < 3; dy++)
      #pragma unroll
      for (int dx = 0; dx < 3; dx++)
        p[dy*3+dx] = ib[ry[dy]*Hin + rx[dx]];
    #pragma unroll
    for (int j = 0; j < G; j++) {
      const float* wcc = w + ((size_t)(co0 + j)*Cin + ci)*9;
      #pragma unroll
      for (int k = 0; k < 9; k++) acc[j] += wcc[k] * p[k];
    }
  }

  int pix = y*Hout + x;
  #pragma unroll
  for (int j = 0; j < G; j++) {
    float v = acc[j];
    v = (v >= 0.f) ? v : 0.01f*v;
    out[((size_t)(b*CO) + co0 + j)*(Hout*Hout) + pix] = v;
  }
}

// ---------------- thread-per-pixel upconv for CO=16 layers ----------------
template<int CO>
__global__ void k_upconv(const float* __restrict__ in, float* __restrict__ out,
                         const float* __restrict__ w, const float* __restrict__ bias,
                         int B, int Cin, int Hin)
{
  int Hout = Hin * 2;
  int total = B * Hout * Hout;
  int idx = blockIdx.x*blockDim.x + threadIdx.x;
  if (idx >= total) return;
  int x = idx % Hout;
  int y = (idx / Hout) % Hout;
  int b = idx / (Hout * Hout);

  int ry[3], rx[3];
  #pragma unroll
  for (int d = 0; d < 3; d++) {
    ry[d] = refl_up(y - 1 + d, Hout);
    rx[d] = refl_up(x - 1 + d, Hout);
  }

  float acc[CO];
  #pragma unroll
  for (int co = 0; co < CO; co++) acc[co] = bias[co];

  for (int ci = 0; ci < Cin; ci++) {
    const float* ib = in + ((size_t)(b*Cin) + ci) * (Hin*Hin);
    float p[9];
    #pragma unroll
    for (int dy = 0; dy < 3; dy++)
      #pragma unroll
      for (int dx = 0; dx < 3; dx++)
        p[dy*3+dx] = ib[ry[dy]*Hin + rx[dx]];
    const float* wc = w + ci*9;
    #pragma unroll
    for (int co = 0; co < CO; co++) {
      const float* wcc = wc + co*Cin*9;
      #pragma unroll
      for (int k = 0; k < 9; k++) acc[co] += wcc[k] * p[k];
    }
  }

  int pix = y*Hout + x;
  #pragma unroll
  for (int co = 0; co < CO; co++) {
    float v = acc[co];
    v = (v >= 0.f) ? v : 0.01f*v;
    out[((size_t)(b*CO) + co)*(Hout*Hout) + pix] = v;
  }
}

// ---------------- final: reflect-pad + 3x3 conv (16 -> 6) + tanh ----------------
__global__ void k_final(const float* __restrict__ in, float* __restrict__ out,
                        const float* __restrict__ w, const float* __restrict__ bias)
{
  int idx = blockIdx.x*blockDim.x + threadIdx.x;
  int total = 3 * HWP;
  if (idx >= total) return;
  int x = idx & (WWI-1);
  int y = (idx >> 9) & (HH-1);
  int b = idx / HWP;

  int ry[3], rx[3];
  #pragma unroll
  for (int d = 0; d < 3; d++) {
    int t = y - 1 + d;
    t = (t < 0) ? -t : t;
    ry[d] = (t >= HH) ? (2*(HH-1) - t) : t;
    t = x - 1 + d;
    t = (t < 0) ? -t : t;
    rx[d] = (t >= WWI) ? (2*(WWI-1) - t) : t;
  }

  float acc[6];
  #pragma unroll
  for (int co = 0; co < 6; co++) acc[co] = bias[co];

  for (int ci = 0; ci < 16; ci++) {
    const float* ib = in + ((size_t)(b*16) + ci) * HWP;
    float p[9];
    #pragma unroll
    for (int dy = 0; dy < 3; dy++)
      #pragma unroll
      for (int dx = 0; dx < 3; dx++)
        p[dy*3+dx] = ib[ry[dy]*WWI + rx[dx]];
    const float* wc = w + ci*9;
    #pragma unroll
    for (int co = 0; co < 6; co++) {
      const float* wcc = wc + co*16*9;
      #pragma unroll
      for (int k = 0; k < 9; k++) acc[co] += wcc[k] * p[k];
    }
  }

  int pix = y*WWI + x;
  #pragma unroll
  for (int co = 0; co < 6; co++)
    out[((size_t)(b*6) + co)*HWP + pix] = tanhf(acc[co]);
}

// ---------------- blending ----------------
__global__ void k_blend(const void* __restrict__ xin, const void* __restrict__ neighbors,
                        const int* __restrict__ aidx, const void* __restrict__ albedos,
                        const float* __restrict__ flows, void* __restrict__ out,
                        const int* __restrict__ flag)
{
  int idx = blockIdx.x*blockDim.x + threadIdx.x;
  if (idx >= HWP) return;
  int isbf = flag[0];
  int xo = idx & (WWI-1);
  int yo = idx >> 9;

  float xv[9];
  #pragma unroll
  for (int i = 0; i < 9; i++) xv[i] = ldin(xin, i, isbf);

  float f0[6];
  #pragma unroll
  for (int c = 0; c < 6; c++) f0[c] = flows[(size_t)c*HWP + idx];

  long albbase = (long)aidx[0]*3*HWP;
  float albp[3];
  #pragma unroll
  for (int ch = 0; ch < 3; ch++) albp[ch] = ldin(albedos, albbase + (long)ch*HWP + idx, isbf);

  float num0 = 0.f, num1 = 0.f, num2 = 0.f;
  float wsum = 0.f;

  #pragma unroll
  for (int n = 0; n < 2; n++) {
    float dl = xv[0] - xv[(n+1)*3 + 0];
    float dv = xv[1] - xv[(n+1)*3 + 1];
    float dt = xv[2] - xv[(n+1)*3 + 2];
    bool fl = fabsf(dl) > 0.f;

    float ofx = dl*f0[0] + dv*f0[2] + dt*f0[4];
    float ofy = dl*f0[1] + dv*f0[3] + dt*f0[5];

    float gx = ((-1.f + (2.f/511.f)*(float)xo) + ofx + 1.f)*256.f - 0.5f;
    float gy = ((-1.f + (2.f/511.f)*(float)yo) + ofy + 1.f)*256.f - 0.5f;
    gx = fminf(fmaxf(gx, 0.f), 511.f);
    gy = fminf(fmaxf(gy, 0.f), 511.f);

    float x0f = floorf(gx), y0f = floorf(gy);
    float wx = gx - x0f, wy = gy - y0f;
    int x0i = (int)x0f, y0i = (int)y0f;
    int x1i = min(x0i + 1, WWI-1), y1i = min(y0i + 1, HH-1);

    float cw[4] = {(1.f-wx)*(1.f-wy), wx*(1.f-wy), (1.f-wx)*wy, wx*wy};
    int   cp[4] = {y0i*WWI + x0i, y0i*WWI + x1i, y1i*WWI + x0i, y1i*WWI + x1i};

    long nbase = (long)n*3*HWP;
    const float* Fn = flows + (size_t)(n+1)*6*HWP;

    float s0=0.f,s1=0.f,s2=0.f;
    float l0=0.f,l1=0.f,v0=0.f,v1=0.f,t0=0.f,t1=0.f;
    #pragma unroll
    for (int c = 0; c < 4; c++) {
      int p = cp[c];
      float ww = cw[c];
      float n0 = ldin(neighbors, nbase + p, isbf);
      float n1 = ldin(neighbors, nbase + HWP + p, isbf);
      float n2 = ldin(neighbors, nbase + 2*HWP + p, isbf);
      if (fl) {
        n0 /= ldin(albedos, albbase + p, isbf);
        n1 /= ldin(albedos, albbase + HWP + p, isbf);
        n2 /= ldin(albedos, albbase + 2*HWP + p, isbf);
      }
      s0 += ww*n0; s1 += ww*n1; s2 += ww*n2;
      l0 += ww*Fn[p];             l1 += ww*Fn[HWP + p];
      v0 += ww*Fn[2*HWP + p];     v1 += ww*Fn[3*HWP + p];
      t0 += ww*Fn[4*HWP + p];     t1 += ww*Fn[5*HWP + p];
    }

    float wi0 = fl ? s0*albp[0] : s0;
    float wi1 = fl ? s1*albp[1] : s1;
    float wi2 = fl ? s2*albp[2] : s2;

    float obx = dl*l0 + dv*v0 + dt*t0;
    float oby = dl*l1 + dv*v1 + dt*t1;
    float dist = fabsf(ofx - obx) + fabsf(ofy - oby);
    float wgt = expf(-51.2f * dist);

    wsum += wgt;
    num0 += wgt*wi0; num1 += wgt*wi1; num2 += wgt*wi2;
  }

  float inv = 1.f / (wsum + 1e-5f);
  float r0 = num0*inv, r1 = num1*inv, r2 = num2*inv;
  if (isbf) {
    bf16* o = (bf16*)out;
    o[idx]         = __float2bfloat16(r0);
    o[HWP + idx]   = __float2bfloat16(r1);
    o[2*HWP + idx] = __float2bfloat16(r2);
  } else {
    float* o = (float*)out;
    o[idx]         = r0;
    o[HWP + idx]   = r1;
    o[2*HWP + idx] = r2;
  }
}

// ---------------- launch ----------------
extern "C" void kernel_launch(void* const* d_in, const int* in_sizes, int n_in,
                              void* d_out, int out_size, void* d_ws, size_t ws_size,
                              hipStream_t stream) {
  const void* x         = d_in[0];
  const void* neighbors = d_in[1];
  const int*  aidx      = (const int*)d_in[2];
  const void* wts[10];
  const void* bis[10];
  for (int i = 0; i < 9; i++) { wts[i] = d_in[3+2*i]; bis[i] = d_in[4+2*i]; }
  wts[9] = d_in[21];   // wf
  bis[9] = d_in[22];   // bf
  const void* albedos = d_in[23];

  float* wk    = (float*)d_ws;
  int*   flagp = (int*)d_ws;
  float* wf32  = wk + 8;
  float* bufS  = wk + 122368;
  float* bufA  = wk + 123160;
  float* bufB  = bufA + 4718592;
  size_t need = (size_t)(123160 + 4718592 + 12582912) * 4;
  if (ws_size < need) return;

  const int o_w0=0, o_b0=192, o_w1=256, o_b1=38272, o_w2=38336, o_b2=75200,
            o_w3=75264, o_b3=93696, o_w4=93728, o_b4=102944, o_w5=102976, o_b5=112192,
            o_w6=112224, o_b6=116832, o_w7=116848, o_b7=119152, o_w8=119168, o_b8=121472,
            o_wf=121488, o_bf=122352;

  k_detect<<<1, 256, 0, stream>>>(wts[1], flagp);

  k_convert<<<(122358+255)/256, 256, 0, stream>>>(
      wts[0],bis[0],wts[1],bis[1],wts[2],bis[2],wts[3],bis[3],wts[4],bis[4],
      wts[5],bis[5],wts[6],bis[6],wts[7],bis[7],wts[8],bis[8],wts[9],bis[9],
      wf32, flagp);

  k_layer0<<<1, 256, 0, stream>>>(x, wf32+o_w0, wf32+o_b0, bufS, flagp);

  auto blocks = [](int total){ return (total + 255) / 256; };

  // grouped (G=8) for CO=64/32 layers: no acc spills, parallelism x CO/8
  k_upconv_g<8><<<blocks(3*8*4*4),     256, 0, stream>>>(bufS, bufA, wf32+o_w1, wf32+o_b1, 3, 66, 2, 64);
  k_upconv_g<8><<<blocks(3*8*8*8),     256, 0, stream>>>(bufA, bufB, wf32+o_w2, wf32+o_b2, 3, 64, 4, 64);
  k_upconv_g<8><<<blocks(3*4*16*16),   256, 0, stream>>>(bufB, bufA, wf32+o_w3, wf32+o_b3, 3, 64, 8, 32);
  k_upconv_g<8><<<blocks(3*4*32*32),   256, 0, stream>>>(bufA, bufB, wf32+o_w4, wf32+o_b4, 3, 32, 16, 32);
  k_upconv_g<8><<<blocks(3*4*64*64),   256, 0, stream>>>(bufB, bufA, wf32+o_w5, wf32+o_b5, 3, 32, 32, 32);
  // CO=16 layers: thread-per-pixel, acc[16] fits
  k_upconv<16><<<blocks(3*128*128), 256, 0, stream>>>(bufA, bufB, wf32+o_w6, wf32+o_b6, 3, 32, 64);
  k_upconv<16><<<blocks(3*256*256), 256, 0, stream>>>(bufB, bufA, wf32+o_w7, wf32+o_b7, 3, 16, 128);
  k_upconv<16><<<blocks(3*512*512), 256, 0, stream>>>(bufA, bufB, wf32+o_w8, wf32+o_b8, 3, 16, 256);
  k_final<<<blocks(3*HWP), 256, 0, stream>>>(bufB, bufA, wf32+o_wf, wf32+o_bf);

  k_blend<<<blocks(HWP), 256, 0, stream>>>(x, neighbors, aidx, albedos, bufA, d_out, flagp);
}

// Round 7
// 520.979 us; speedup vs baseline: 3.5001x; 1.2247x over previous
//
#include <hip/hip_runtime.h>
#include <hip/hip_bf16.h>
#include <math.h>

// All inputs and the output are FLOAT32 (reference dtype). The "bf16" in the
// harness label is a literal string, not a dtype indicator. R2/R3 passed via
// the runtime-detector's fp32 path; hard-coding bf16 (R4/R6) produced NaN.

#define HH 512
#define WWI 512
#define HWP (HH*WWI)

// ---------------- layer 0: 1x1 conv on upsampled 2x2 + leakyrelu + coordconv ----------------
__global__ void k_layer0(const float* __restrict__ xin, const float* __restrict__ w,
                         const float* __restrict__ bias, float* __restrict__ out)
{
  for (int idx = threadIdx.x; idx < 3*66*4; idx += blockDim.x) {
    int pos = idx & 3;
    int c = (idx >> 2) % 66;
    int b = idx / (66*4);
    float v;
    if (c < 64) {
      float a = bias[c];
      #pragma unroll
      for (int ci = 0; ci < 3; ci++) a += w[c*3+ci] * xin[b*3+ci];
      v = (a >= 0.f) ? a : 0.01f*a;
    } else {
      int xx = pos & 1, yy = pos >> 1;
      v = (c == 64) ? 2.f*(float)xx : 2.f*(float)yy;
    }
    out[idx] = v;
  }
}

__device__ __forceinline__ int refl_up(int t, int n) {
  t = (t < 0) ? -t : t;
  t = (t >= n) ? (2*(n-1) - t) : t;
  return t >> 1;
}

// ---------------- LDS conv: upsample x2 + reflect-pad + 3x3 + leakyrelu ----------------
// block = (b, co-slice COB, row-tile TR). Source rows staged: [r0, r0+SPAN).
// SPAN = min(Hin, TR/2+2) computed identically on host and device-args.
template<int G>
__global__ void k_conv_lds(const float* __restrict__ in, float* __restrict__ out,
                           const float* __restrict__ w, const float* __restrict__ bias,
                           int B, int Cin, int CO, int COB, int Hin, int TR, int SPAN)
{
  extern __shared__ float lds[];
  const int Hout = Hin * 2;
  const int rowTiles = Hout / TR;
  const int coTiles = CO / COB;
  int bid = blockIdx.x;
  int tile = bid % rowTiles;
  int cot  = (bid / rowTiles) % coTiles;
  int b    = bid / (rowTiles * coTiles);
  int tr0  = tile * TR;
  int co_base = cot * COB;

  int r0 = tr0/2 - 1;
  if (r0 < 0) r0 = 0;
  if (r0 > Hin - SPAN) r0 = Hin - SPAN;

  float* wlds = lds;                    // COB*Cin*9
  float* blds = wlds + COB*Cin*9;       // COB
  float* ilds = blds + COB;             // Cin*SPAN*Hin

  int nt = blockDim.x, tid = threadIdx.x;

  const float* wsrc = w + (size_t)co_base*Cin*9;
  for (int i = tid; i < COB*Cin*9; i += nt) wlds[i] = wsrc[i];
  for (int i = tid; i < COB; i += nt) blds[i] = bias[co_base + i];
  int icount = Cin*SPAN*Hin;
  for (int i = tid; i < icount; i += nt) {
    int col = i % Hin;
    int r = (i / Hin) % SPAN;
    int ci = i / (Hin*SPAN);
    ilds[i] = in[(((size_t)b*Cin + ci)*Hin + (r0 + r))*Hin + col];
  }
  __syncthreads();

  int npix = TR * Hout;
  int ngr = COB / G;
  int items = ngr * npix;
  for (int it = tid; it < items; it += nt) {
    int pix = it % npix;
    int cg = it / npix;
    int x = pix % Hout;
    int y = tr0 + pix / Hout;

    int ry[3], rx[3];
    #pragma unroll
    for (int d = 0; d < 3; d++) {
      int s = refl_up(y - 1 + d, Hout) - r0;
      s = (s < 0) ? 0 : s;
      s = (s > SPAN-1) ? SPAN-1 : s;
      ry[d] = s;
      rx[d] = refl_up(x - 1 + d, Hout);
    }

    float acc[G];
    #pragma unroll
    for (int j = 0; j < G; j++) acc[j] = blds[cg*G + j];

    for (int ci = 0; ci < Cin; ci++) {
      const float* ib = ilds + (size_t)ci*SPAN*Hin;
      float p[9];
      #pragma unroll
      for (int dy = 0; dy < 3; dy++)
        #pragma unroll
        for (int dx = 0; dx < 3; dx++)
          p[dy*3+dx] = ib[ry[dy]*Hin + rx[dx]];
      const float* wc = wlds + ((size_t)(cg*G)*Cin + ci)*9;
      #pragma unroll
      for (int j = 0; j < G; j++) {
        #pragma unroll
        for (int k = 0; k < 9; k++) acc[j] += wc[(size_t)j*Cin*9 + k] * p[k];
      }
    }

    #pragma unroll
    for (int j = 0; j < G; j++) {
      float v = acc[j];
      v = (v >= 0.f) ? v : 0.01f*v;
      out[(((size_t)b*CO + co_base + cg*G + j)*Hout + y)*Hout + x] = v;
    }
  }
}

// ---------------- thread-per-pixel upconv (R3-proven) for CO=16 layers ----------------
template<int CO>
__global__ void k_upconv(const float* __restrict__ in, float* __restrict__ out,
                         const float* __restrict__ w, const float* __restrict__ bias,
                         int B, int Cin, int Hin)
{
  int Hout = Hin * 2;
  int total = B * Hout * Hout;
  int idx = blockIdx.x*blockDim.x + threadIdx.x;
  if (idx >= total) return;
  int x = idx % Hout;
  int y = (idx / Hout) % Hout;
  int b = idx / (Hout * Hout);

  int ry[3], rx[3];
  #pragma unroll
  for (int d = 0; d < 3; d++) {
    ry[d] = refl_up(y - 1 + d, Hout);
    rx[d] = refl_up(x - 1 + d, Hout);
  }

  float acc[CO];
  #pragma unroll
  for (int co = 0; co < CO; co++) acc[co] = bias[co];

  for (int ci = 0; ci < Cin; ci++) {
    const float* ib = in + ((size_t)(b*Cin) + ci) * (Hin*Hin);
    float p[9];
    #pragma unroll
    for (int dy = 0; dy < 3; dy++)
      #pragma unroll
      for (int dx = 0; dx < 3; dx++)
        p[dy*3+dx] = ib[ry[dy]*Hin + rx[dx]];
    const float* wc = w + ci*9;
    #pragma unroll
    for (int co = 0; co < CO; co++) {
      const float* wcc = wc + co*Cin*9;
      #pragma unroll
      for (int k = 0; k < 9; k++) acc[co] += wcc[k] * p[k];
    }
  }

  int pix = y*Hout + x;
  #pragma unroll
  for (int co = 0; co < CO; co++) {
    float v = acc[co];
    v = (v >= 0.f) ? v : 0.01f*v;
    out[((size_t)(b*CO) + co)*(Hout*Hout) + pix] = v;
  }
}

// ---------------- final: reflect-pad + 3x3 conv (16 -> 6) + tanh ----------------
__global__ void k_final(const float* __restrict__ in, float* __restrict__ out,
                        const float* __restrict__ w, const float* __restrict__ bias)
{
  int idx = blockIdx.x*blockDim.x + threadIdx.x;
  int total = 3 * HWP;
  if (idx >= total) return;
  int x = idx & (WWI-1);
  int y = (idx >> 9) & (HH-1);
  int b = idx / HWP;

  int ry[3], rx[3];
  #pragma unroll
  for (int d = 0; d < 3; d++) {
    int t = y - 1 + d;
    t = (t < 0) ? -t : t;
    ry[d] = (t >= HH) ? (2*(HH-1) - t) : t;
    t = x - 1 + d;
    t = (t < 0) ? -t : t;
    rx[d] = (t >= WWI) ? (2*(WWI-1) - t) : t;
  }

  float acc[6];
  #pragma unroll
  for (int co = 0; co < 6; co++) acc[co] = bias[co];

  for (int ci = 0; ci < 16; ci++) {
    const float* ib = in + ((size_t)(b*16) + ci) * HWP;
    float p[9];
    #pragma unroll
    for (int dy = 0; dy < 3; dy++)
      #pragma unroll
      for (int dx = 0; dx < 3; dx++)
        p[dy*3+dx] = ib[ry[dy]*WWI + rx[dx]];
    const float* wc = w + ci*9;
    #pragma unroll
    for (int co = 0; co < 6; co++) {
      const float* wcc = wc + co*16*9;
      #pragma unroll
      for (int k = 0; k < 9; k++) acc[co] += wcc[k] * p[k];
    }
  }

  int pix = y*WWI + x;
  #pragma unroll
  for (int co = 0; co < 6; co++)
    out[((size_t)(b*6) + co)*HWP + pix] = tanhf(acc[co]);
}

// ---------------- blending: fused grid-sample + weighting (all fp32) ----------------
__global__ void k_blend(const float* __restrict__ xin, const float* __restrict__ neighbors,
                        const int* __restrict__ aidx, const float* __restrict__ albedos,
                        const float* __restrict__ flows, float* __restrict__ out)
{
  int idx = blockIdx.x*blockDim.x + threadIdx.x;
  if (idx >= HWP) return;
  int xo = idx & (WWI-1);
  int yo = idx >> 9;

  float xv[9];
  #pragma unroll
  for (int i = 0; i < 9; i++) xv[i] = xin[i];

  float f0[6];
  #pragma unroll
  for (int c = 0; c < 6; c++) f0[c] = flows[(size_t)c*HWP + idx];

  const float* alb = albedos + (size_t)aidx[0]*3*HWP;
  float albp[3];
  #pragma unroll
  for (int ch = 0; ch < 3; ch++) albp[ch] = alb[(size_t)ch*HWP + idx];

  float num0 = 0.f, num1 = 0.f, num2 = 0.f;
  float wsum = 0.f;

  #pragma unroll
  for (int n = 0; n < 2; n++) {
    float dl = xv[0] - xv[(n+1)*3 + 0];
    float dv = xv[1] - xv[(n+1)*3 + 1];
    float dt = xv[2] - xv[(n+1)*3 + 2];
    bool fl = fabsf(dl) > 0.f;

    float ofx = dl*f0[0] + dv*f0[2] + dt*f0[4];
    float ofy = dl*f0[1] + dv*f0[3] + dt*f0[5];

    float gx = ((-1.f + (2.f/511.f)*(float)xo) + ofx + 1.f)*256.f - 0.5f;
    float gy = ((-1.f + (2.f/511.f)*(float)yo) + ofy + 1.f)*256.f - 0.5f;
    gx = fminf(fmaxf(gx, 0.f), 511.f);
    gy = fminf(fmaxf(gy, 0.f), 511.f);

    float x0f = floorf(gx), y0f = floorf(gy);
    float wx = gx - x0f, wy = gy - y0f;
    int x0i = (int)x0f, y0i = (int)y0f;
    int x1i = min(x0i + 1, WWI-1), y1i = min(y0i + 1, HH-1);

    float cw[4] = {(1.f-wx)*(1.f-wy), wx*(1.f-wy), (1.f-wx)*wy, wx*wy};
    int   cp[4] = {y0i*WWI + x0i, y0i*WWI + x1i, y1i*WWI + x0i, y1i*WWI + x1i};

    const float* nb = neighbors + (size_t)n*3*HWP;
    const float* Fn = flows + (size_t)(n+1)*6*HWP;

    float s0=0.f,s1=0.f,s2=0.f;
    float l0=0.f,l1=0.f,v0=0.f,v1=0.f,t0=0.f,t1=0.f;
    #pragma unroll
    for (int c = 0; c < 4; c++) {
      int p = cp[c];
      float ww = cw[c];
      float n0 = nb[p];
      float n1 = nb[HWP + p];
      float n2 = nb[2*HWP + p];
      if (fl) {
        n0 /= alb[p];
        n1 /= alb[HWP + p];
        n2 /= alb[2*HWP + p];
      }
      s0 += ww*n0; s1 += ww*n1; s2 += ww*n2;
      l0 += ww*Fn[p];             l1 += ww*Fn[HWP + p];
      v0 += ww*Fn[2*HWP + p];     v1 += ww*Fn[3*HWP + p];
      t0 += ww*Fn[4*HWP + p];     t1 += ww*Fn[5*HWP + p];
    }

    float wi0 = fl ? s0*albp[0] : s0;
    float wi1 = fl ? s1*albp[1] : s1;
    float wi2 = fl ? s2*albp[2] : s2;

    float obx = dl*l0 + dv*v0 + dt*t0;
    float oby = dl*l1 + dv*v1 + dt*t1;
    float dist = fabsf(ofx - obx) + fabsf(ofy - oby);
    float wgt = expf(-51.2f * dist);

    wsum += wgt;
    num0 += wgt*wi0; num1 += wgt*wi1; num2 += wgt*wi2;
  }

  float inv = 1.f / (wsum + 1e-5f);
  out[idx]         = num0*inv;
  out[HWP + idx]   = num1*inv;
  out[2*HWP + idx] = num2*inv;
}

// ---------------- launch ----------------
extern "C" void kernel_launch(void* const* d_in, const int* in_sizes, int n_in,
                              void* d_out, int out_size, void* d_ws, size_t ws_size,
                              hipStream_t stream) {
  const float* x         = (const float*)d_in[0];
  const float* neighbors = (const float*)d_in[1];
  const int*   aidx      = (const int*)d_in[2];
  const float* wts[10];
  const float* bis[10];
  for (int i = 0; i < 9; i++) { wts[i] = (const float*)d_in[3+2*i]; bis[i] = (const float*)d_in[4+2*i]; }
  wts[9] = (const float*)d_in[21];   // wf
  bis[9] = (const float*)d_in[22];   // bf
  const float* albedos = (const float*)d_in[23];

  float* wk   = (float*)d_ws;
  float* bufS = wk;                   // 792 floats (layer0 out)
  float* bufA = wk + 800;             // up to 4,718,592 floats
  float* bufB = bufA + 4718592;       // up to 12,582,912 floats
  size_t need = (size_t)(800 + 4718592 + 12582912) * 4;
  if (ws_size < need) return;

  k_layer0<<<1, 256, 0, stream>>>(x, wts[0], bis[0], bufS);

  auto spanOf = [](int Hin, int TR) { int s = TR/2 + 2; return (s > Hin) ? Hin : s; };
  auto ldsB = [&](int COB, int Cin, int Hin, int TR) {
    return (size_t)(COB*Cin*9 + COB + Cin*spanOf(Hin,TR)*Hin) * 4;
  };

  // L1: Cin=66 CO=64 Hin=2  | COB=16 TR=4 G=1 | blocks 3*4*1=12
  k_conv_lds<1><<<12, 256, ldsB(16,66,2,4), stream>>>(bufS, bufA, wts[1], bis[1],
                                                      3, 66, 64, 16, 2, 4, spanOf(2,4));
  // L2: Cin=64 CO=64 Hin=4  | COB=8 TR=8 G=1 | blocks 3*8*1=24
  k_conv_lds<1><<<24, 256, ldsB(8,64,4,8), stream>>>(bufA, bufB, wts[2], bis[2],
                                                     3, 64, 64, 8, 4, 8, spanOf(4,8));
  // L3: Cin=64 CO=32 Hin=8  | COB=4 TR=16 G=2 | blocks 3*8*1=24
  k_conv_lds<2><<<24, 256, ldsB(4,64,8,16), stream>>>(bufB, bufA, wts[3], bis[3],
                                                      3, 64, 32, 4, 8, 16, spanOf(8,16));
  // L4: Cin=32 CO=32 Hin=16 | COB=8 TR=8 G=2 | blocks 3*4*4=48
  k_conv_lds<2><<<48, 256, ldsB(8,32,16,8), stream>>>(bufA, bufB, wts[4], bis[4],
                                                      3, 32, 32, 8, 16, 8, spanOf(16,8));
  // L5: Cin=32 CO=32 Hin=32 | COB=8 TR=8 G=4 | blocks 3*4*8=96
  k_conv_lds<4><<<96, 256, ldsB(8,32,32,8), stream>>>(bufB, bufA, wts[5], bis[5],
                                                      3, 32, 32, 8, 32, 8, spanOf(32,8));

  auto blocks = [](int total){ return (total + 255) / 256; };
  // L6-L8: R3-proven global-memory kernels
  k_upconv<16><<<blocks(3*128*128), 256, 0, stream>>>(bufA, bufB, wts[6], bis[6], 3, 32, 64);
  k_upconv<16><<<blocks(3*256*256), 256, 0, stream>>>(bufB, bufA, wts[7], bis[7], 3, 16, 128);
  k_upconv<16><<<blocks(3*512*512), 256, 0, stream>>>(bufA, bufB, wts[8], bis[8], 3, 16, 256);

  k_final<<<blocks(3*HWP), 256, 0, stream>>>(bufB, bufA, wts[9], bis[9]);
  k_blend<<<blocks(HWP), 256, 0, stream>>>(x, neighbors, aidx, albedos, bufA, (float*)d_out);
}